// Round 5
// baseline (327.667 us; speedup 1.0000x reference)
//
#include <hip/hip_runtime.h>
#include <hip/hip_bf16.h>
#include <cstdint>

#define B_ 4
#define H_ 80
#define W_ 80
#define CH_ 256
#define NC_ 22
#define DIM_ 256
#define NPIX (B_*H_*W_)

typedef unsigned short ushort;
typedef __attribute__((ext_vector_type(8))) short short8;     // 8 bf16 = 4 VGPR
typedef __attribute__((ext_vector_type(4))) float floatx4;    // MFMA C/D frag

static __device__ inline ushort f2bf(float v) {
    __hip_bfloat16 h = __float2bfloat16(v);   // RNE
    ushort r;
    __builtin_memcpy(&r, &h, 2);
    return r;
}
static __device__ inline unsigned pk2(float a, float b) {
    return (unsigned)f2bf(a) | ((unsigned)f2bf(b) << 16);
}

// ---------------------------------------------------------------------------
// prep: weight repack cw[c][k][d] f32 -> wbT[k][d][c] bf16 via LDS transpose.
// 72 blocks = (k, 32-c chunk). Coalesced 1KB row reads, 64B packed writes.
// ---------------------------------------------------------------------------
__global__ __launch_bounds__(256) void prep(const float* __restrict__ cw,
                                            ushort* __restrict__ wbT)
{
    __shared__ ushort ls[32][260];
    const int k  = blockIdx.x / 8;
    const int c0 = (blockIdx.x % 8) * 32;
    const int c  = threadIdx.x >> 3;         // 0..31
    const int sg = threadIdx.x & 7;          // 0..7

    const float* src = cw + ((size_t)(c0 + c) * 9 + k) * DIM_ + sg * 32;
    #pragma unroll
    for (int e = 0; e < 32; e += 4) {
        float4 v = *(const float4*)(src + e);
        unsigned* dst = (unsigned*)&ls[c][sg * 32 + e];
        dst[0] = pk2(v.x, v.y);
        dst[1] = pk2(v.z, v.w);
    }
    __syncthreads();

    const int d = threadIdx.x;
    ushort tmp[32];
    #pragma unroll
    for (int cc = 0; cc < 32; ++cc) tmp[cc] = ls[cc][d];
    uint4 o[4];
    __builtin_memcpy(o, tmp, 64);
    uint4* dst = (uint4*)(wbT + ((size_t)k * 256 + d) * 256 + c0);
    dst[0] = o[0]; dst[1] = o[1]; dst[2] = o[2]; dst[3] = o[3];
}

// ---------------------------------------------------------------------------
// conv4: block = image row (80 px) x 128 d; grid (2, 320); 4 waves.
// 6 phases (i=0..2 x cc={0,128}): stage halo'd A-tile (84 slot-rows x 128 ch
// bf16, XOR-swizzled, row stride 256B) ONCE from f32 x (pack in-flight),
// then 3 taps (j=0,1,2, k=3i+j) of 40 MFMAs/wave read it at row-offset j.
// Staging is VGPR round-trip (NO global_load_lds: LDS-DMA defeated L3 and
// caused phantom HBM writes in round 4). Per tap: Breg[8] global->reg from
// L2-hot wbT, issued BEFORE the 2 staged x-chunks so the tap's vmcnt wait
// does not drain the staging queue. Per-tap scale s_k[m] on the C-fragment.
// One barrier per phase.  LDS 45.9 KB -> 3 blocks/CU, all 640 co-resident.
// ---------------------------------------------------------------------------
__global__ __launch_bounds__(256, 3) void conv4(const float* __restrict__ x,
                                                const float* __restrict__ seg,
                                                const ushort* __restrict__ wbT,
                                                float* __restrict__ out)
{
    __shared__ ushort xs[2][84 * 128];    // 43 KB; slot(row,s) holds chunk (s&8)|((s^row)&7)
    __shared__ float  sl[9][80];          // 2.88 KB

    const int tid  = threadIdx.x;
    const int lane = tid & 63;
    const int wv   = tid >> 6;
    const int ln   = lane & 15;
    const int quad = lane >> 4;
    const int d0   = blockIdx.x * 128;
    const int rt   = blockIdx.y;          // b*H + h
    const int b    = rt / H_;
    const int h    = rt % H_;

    // staging: 1344 chunks (84 rows x 16 slots); thread handles q = tid + 256*r
    float4 fa[2], fb[2];
    bool   okc[2];

    auto sload = [&](int p, int r0) {     // issue global loads for chunks r0,r0+1
        const int i  = p >> 1;
        const int cc = (p & 1) * 128;
        const int rr = h + i - 1;
        const bool rowok = (rr >= 0) && (rr < H_);
        #pragma unroll
        for (int t = 0; t < 2; ++t) {
            const int q   = tid + 256 * (r0 + t);
            const int row = q >> 4;       // slot row 0..83
            const int cb  = q & 15;       // slot column
            const int col = row - 1;      // image column
            const bool v = (q < 1344) && rowok && (col >= 0) && (col < W_);
            okc[t] = v;
            if (v) {
                const int ch2 = (cb & 8) | ((cb ^ row) & 7);   // content chunk
                const float* f = x + (((size_t)(b * H_ + rr)) * W_ + col) * CH_
                                   + cc + ch2 * 8;
                fa[t] = *(const float4*)f;
                fb[t] = *(const float4*)(f + 4);
            }
        }
    };
    auto sstore = [&](int buf, int r0) {  // pack + LDS write for chunks r0,r0+1
        #pragma unroll
        for (int t = 0; t < 2; ++t) {
            const int q = tid + 256 * (r0 + t);
            if (q < 1344) {
                const int row = q >> 4;
                const int cb  = q & 15;
                uint4 v = okc[t]
                    ? make_uint4(pk2(fa[t].x, fa[t].y), pk2(fa[t].z, fa[t].w),
                                 pk2(fb[t].x, fb[t].y), pk2(fb[t].z, fb[t].w))
                    : make_uint4(0u, 0u, 0u, 0u);
                *(uint4*)&xs[buf][row * 128 + cb * 8] = v;
            }
        }
    };

    // ---- prologue: stage phase 0 into buf 0; fused sel into sl ----
    sload(0, 0); sstore(0, 0);
    sload(0, 2); sstore(0, 2);
    sload(0, 4); sstore(0, 4);

    if (tid < W_) {
        const int m = tid;
        const float2* c2 = (const float2*)(seg + ((size_t)(b * H_ + h) * W_ + m) * NC_);
        float cv[NC_];
        #pragma unroll
        for (int c = 0; c < NC_ / 2; ++c) { float2 v = c2[c]; cv[2*c] = v.x; cv[2*c+1] = v.y; }
        float mx = -1e30f;
        #pragma unroll
        for (int c = 0; c < NC_; ++c) mx = fmaxf(mx, cv[c]);
        float sel[9];
        int cnt = 0;
        #pragma unroll
        for (int k = 0; k < 9; ++k) {
            int i = k / 3, j = k % 3;
            int hh = h + i - 1, ww = m + j - 1;
            float s = 0.f;
            if (hh >= 0 && hh < H_ && ww >= 0 && ww < W_) {
                const float2* n2 = (const float2*)(seg + ((size_t)(b * H_ + hh) * W_ + ww) * NC_);
                #pragma unroll
                for (int c = 0; c < NC_ / 2; ++c) {
                    float2 v = n2[c];
                    s += (cv[2*c]   == mx) ? v.x : 0.f;
                    s += (cv[2*c+1] == mx) ? v.y : 0.f;
                }
            }
            sel[k] = s;
            cnt += (s != 0.f) ? 1 : 0;
        }
        float norm = (cnt > 0) ? 9.f / (float)cnt : 0.f;
        #pragma unroll
        for (int k = 0; k < 9; ++k) sl[k][m] = sel[k] * norm;
    }

    floatx4 O[5][2];
    #pragma unroll
    for (int im = 0; im < 5; ++im)
        #pragma unroll
        for (int jn = 0; jn < 2; ++jn)
            O[im][jn] = (floatx4){0.f, 0.f, 0.f, 0.f};

    __syncthreads();

    // ---- main loop ----
    for (int p = 0; p < 6; ++p) {
        const int buf = p & 1;
        const int i   = p >> 1;
        const int cc  = (p & 1) * 128;

        #pragma unroll
        for (int j = 0; j < 3; ++j) {
            const int k = 3 * i + j;

            // B first (oldest in vmem queue -> MFMA wait doesn't drain staging)
            short8 Breg[8];               // [kk][jn]
            #pragma unroll
            for (int kk = 0; kk < 4; ++kk)
                #pragma unroll
                for (int jn = 0; jn < 2; ++jn)
                    Breg[kk * 2 + jn] = *(const short8*)(wbT
                        + ((size_t)k * 256 + d0 + wv * 32 + jn * 16 + ln) * 256
                        + cc + kk * 32 + quad * 8);

            if (p < 5) sload(p + 1, 2 * j);   // next phase, 2 chunks, in flight

            floatx4 P[5][2];
            #pragma unroll
            for (int im = 0; im < 5; ++im)
                #pragma unroll
                for (int jn = 0; jn < 2; ++jn)
                    P[im][jn] = (floatx4){0.f, 0.f, 0.f, 0.f};

            #pragma unroll
            for (int kk = 0; kk < 4; ++kk) {
                short8 a[5];
                #pragma unroll
                for (int im = 0; im < 5; ++im) {
                    const int rho = im * 16 + ln + j;
                    const int Gc  = 4 * kk + quad;
                    const int ch  = (Gc & 8) | ((Gc ^ rho) & 7);
                    a[im] = *(const short8*)&xs[buf][rho * 128 + ch * 8];
                }
                #pragma unroll
                for (int im = 0; im < 5; ++im)
                    #pragma unroll
                    for (int jn = 0; jn < 2; ++jn)
                        P[im][jn] = __builtin_amdgcn_mfma_f32_16x16x32_bf16(
                            a[im], Breg[kk * 2 + jn], P[im][jn], 0, 0, 0);
            }

            if (p < 5) sstore(buf ^ 1, 2 * j);   // pack+write after MFMA issue

            // O += s_k[m] * P   (row m = im*16 + quad*4 + e; broadcast reads)
            #pragma unroll
            for (int im = 0; im < 5; ++im) {
                const floatx4 sv = *(const floatx4*)&sl[k][im * 16 + quad * 4];
                #pragma unroll
                for (int jn = 0; jn < 2; ++jn) {
                    O[im][jn][0] += sv[0] * P[im][jn][0];
                    O[im][jn][1] += sv[1] * P[im][jn][1];
                    O[im][jn][2] += sv[2] * P[im][jn][2];
                    O[im][jn][3] += sv[3] * P[im][jn][3];
                }
            }
        }
        __syncthreads();                  // buf consumed; buf^1 writes visible
    }

    // epilogue: C/D layout col(d)=lane&15, row(m)=quad*4+reg
    #pragma unroll
    for (int im = 0; im < 5; ++im) {
        #pragma unroll
        for (int jn = 0; jn < 2; ++jn) {
            const int dd = d0 + wv * 32 + jn * 16 + ln;
            #pragma unroll
            for (int r = 0; r < 4; ++r) {
                const int m = im * 16 + quad * 4 + r;
                out[((size_t)(rt * W_ + m)) * DIM_ + dd] = O[im][jn][r];
            }
        }
    }
}

extern "C" void kernel_launch(void* const* d_in, const int* in_sizes, int n_in,
                              void* d_out, int out_size, void* d_ws, size_t ws_size,
                              hipStream_t stream)
{
    const float* x   = (const float*)d_in[0];   // (4,80,80,256) f32
    const float* seg = (const float*)d_in[1];   // (4,80,80,22)  f32
    const float* cw  = (const float*)d_in[2];   // (256,3,3,256) f32
    float* out = (float*)d_out;

    ushort* wbT = (ushort*)d_ws;                // 9*256*256*2 = 1,179,648 B only

    prep<<<dim3(72), dim3(256), 0, stream>>>(cw, wbT);
    conv4<<<dim3(2, B_ * H_), dim3(256), 0, stream>>>(x, seg, wbT, out);
}

// Round 6
// 259.205 us; speedup vs baseline: 1.2641x; 1.2641x over previous
//
#include <hip/hip_runtime.h>
#include <hip/hip_bf16.h>
#include <cstdint>

#define B_ 4
#define H_ 80
#define W_ 80
#define CH_ 256
#define NC_ 22
#define DIM_ 256
#define NPIX (B_*H_*W_)

typedef unsigned short ushort;
typedef __attribute__((ext_vector_type(8))) short short8;     // 8 bf16 = 4 VGPR
typedef __attribute__((ext_vector_type(4))) float floatx4;    // MFMA C/D frag

static __device__ inline ushort f2bf(float v) {
    __hip_bfloat16 h = __float2bfloat16(v);   // RNE
    ushort r;
    __builtin_memcpy(&r, &h, 2);
    return r;
}
static __device__ inline unsigned pk2(float a, float b) {
    return (unsigned)f2bf(a) | ((unsigned)f2bf(b) << 16);
}

// ---------------------------------------------------------------------------
// prep: blocks 0..71        -> weight repack cw[c][k][d] f32 -> wbT[k][d][c] bf16
//       blocks 72..72+NXB-1 -> x f32 -> xb bf16  (skipped when XB16 off)
// ---------------------------------------------------------------------------
#define NXB (NPIX * CH_ / (256 * 8))     // 3200
__global__ __launch_bounds__(256) void prep(const float* __restrict__ cw,
                                            const float* __restrict__ x,
                                            ushort* __restrict__ wbT,
                                            ushort* __restrict__ xb)
{
    __shared__ ushort ls[32][260];
    if (blockIdx.x >= 72) {
        const int bid = blockIdx.x - 72;
        const size_t idx = ((size_t)bid * 256 + threadIdx.x) * 8;
        const float4* s = (const float4*)(x + idx);
        float4 a = s[0], b = s[1];
        *(uint4*)(xb + idx) = make_uint4(pk2(a.x, a.y), pk2(a.z, a.w),
                                         pk2(b.x, b.y), pk2(b.z, b.w));
        return;
    }
    const int k  = blockIdx.x / 8;
    const int c0 = (blockIdx.x % 8) * 32;
    const int c  = threadIdx.x >> 3;         // 0..31
    const int sg = threadIdx.x & 7;          // 0..7

    const float* src = cw + ((size_t)(c0 + c) * 9 + k) * DIM_ + sg * 32;
    #pragma unroll
    for (int e = 0; e < 32; e += 4) {
        float4 v = *(const float4*)(src + e);
        unsigned* dst = (unsigned*)&ls[c][sg * 32 + e];
        dst[0] = pk2(v.x, v.y);
        dst[1] = pk2(v.z, v.w);
    }
    __syncthreads();

    const int d = threadIdx.x;
    ushort tmp[32];
    #pragma unroll
    for (int cc = 0; cc < 32; ++cc) tmp[cc] = ls[cc][d];
    uint4 o[4];
    __builtin_memcpy(o, tmp, 64);
    uint4* dst = (uint4*)(wbT + ((size_t)k * 256 + d) * 256 + c0);
    dst[0] = o[0]; dst[1] = o[1]; dst[2] = o[2]; dst[3] = o[3];
}

// ---------------------------------------------------------------------------
// conv5: conv4's compute structure on round-3's memory configuration.
// Block = image row (80 px) x 128 d.  grid(320, 2): blockIdx.x = rt = b*H+h,
// blockIdx.y = d-half.  320 % 8 == 0  ->  the two d-halves of a row (linear
// ids rt and rt+320) land on the SAME XCD and share staged x-lines + wbT in
// that XCD's L2 (round-3-validated: FETCH 26 MB; rounds 4/5's grid(2,320)
// split the pair across XCDs -> FETCH 334 MB).
// 6 phases (i=0..2 x cc={0,128}): stage halo'd A-tile (84 slot-rows x 128 ch
// bf16 from xb, XOR-swizzled, row stride 256 B) ONCE, then 3 taps (j=0,1,2,
// k=3i+j) of 40 MFMAs/wave read it at row-offset j.  B: 8 short8 regs per
// tap from L2-hot wbT, issued BEFORE staging loads so the MFMA's vmcnt wait
// does not drain the staging queue.  Per-tap scale s_k[m] on the C-fragment
// (fp32).  One barrier per phase.  LDS 45.9 KB -> 3 blocks/CU.
// ---------------------------------------------------------------------------
template<bool XB16>
__global__ __launch_bounds__(256, 3) void conv5(const float* __restrict__ x,
                                                const ushort* __restrict__ xb,
                                                const float* __restrict__ seg,
                                                const ushort* __restrict__ wbT,
                                                float* __restrict__ out)
{
    __shared__ ushort xs[2][84 * 128];    // 43 KB; slot(row,s) holds chunk (s&8)|((s^row)&7)
    __shared__ float  sl[9][80];          // 2.88 KB

    const int tid  = threadIdx.x;
    const int lane = tid & 63;
    const int wv   = tid >> 6;
    const int ln   = lane & 15;
    const int quad = lane >> 4;
    const int rt   = blockIdx.x;          // b*H + h
    const int d0   = blockIdx.y * 128;
    const int b    = rt / H_;
    const int h    = rt % H_;

    // staging: 1344 chunks (84 rows x 16 slots); thread handles q = tid + 256*r
    uint4  sg[2];
    float4 fa[2], fb[2];
    bool   okc[2];

    auto sload = [&](int p, int r0) {     // issue global loads for chunks r0,r0+1
        const int i  = p >> 1;
        const int cc = (p & 1) * 128;
        const int rr = h + i - 1;
        const bool rowok = (rr >= 0) && (rr < H_);
        #pragma unroll
        for (int t = 0; t < 2; ++t) {
            const int q   = tid + 256 * (r0 + t);
            const int row = q >> 4;       // slot row 0..83
            const int cb  = q & 15;       // slot column
            const int col = row - 1;      // image column
            const bool v = (q < 1344) && rowok && (col >= 0) && (col < W_);
            okc[t] = v;
            if (v) {
                const int ch2 = (cb & 8) | ((cb ^ row) & 7);   // content chunk
                const size_t gp = ((size_t)(b * H_ + rr)) * W_ + col;
                if (XB16) {
                    sg[t] = *(const uint4*)(xb + gp * CH_ + cc + ch2 * 8);
                } else {
                    const float* f = x + gp * CH_ + cc + ch2 * 8;
                    fa[t] = *(const float4*)f;
                    fb[t] = *(const float4*)(f + 4);
                }
            }
        }
    };
    auto sstore = [&](int buf, int r0) {  // pack + LDS write for chunks r0,r0+1
        #pragma unroll
        for (int t = 0; t < 2; ++t) {
            const int q = tid + 256 * (r0 + t);
            if (q < 1344) {
                const int row = q >> 4;
                const int cb  = q & 15;
                uint4 v;
                if (XB16) {
                    v = okc[t] ? sg[t] : make_uint4(0u, 0u, 0u, 0u);
                } else {
                    v = okc[t]
                        ? make_uint4(pk2(fa[t].x, fa[t].y), pk2(fa[t].z, fa[t].w),
                                     pk2(fb[t].x, fb[t].y), pk2(fb[t].z, fb[t].w))
                        : make_uint4(0u, 0u, 0u, 0u);
                }
                *(uint4*)&xs[buf][row * 128 + cb * 8] = v;
            }
        }
    };

    // ---- prologue: stage phase 0 into buf 0; fused sel into sl ----
    sload(0, 0); sstore(0, 0);
    sload(0, 2); sstore(0, 2);
    sload(0, 4); sstore(0, 4);

    if (tid < W_) {
        const int m = tid;
        const float2* c2 = (const float2*)(seg + ((size_t)(b * H_ + h) * W_ + m) * NC_);
        float cv[NC_];
        #pragma unroll
        for (int c = 0; c < NC_ / 2; ++c) { float2 v = c2[c]; cv[2*c] = v.x; cv[2*c+1] = v.y; }
        float mx = -1e30f;
        #pragma unroll
        for (int c = 0; c < NC_; ++c) mx = fmaxf(mx, cv[c]);
        float sel[9];
        int cnt = 0;
        #pragma unroll
        for (int k = 0; k < 9; ++k) {
            int i = k / 3, j = k % 3;
            int hh = h + i - 1, ww = m + j - 1;
            float s = 0.f;
            if (hh >= 0 && hh < H_ && ww >= 0 && ww < W_) {
                const float2* n2 = (const float2*)(seg + ((size_t)(b * H_ + hh) * W_ + ww) * NC_);
                #pragma unroll
                for (int c = 0; c < NC_ / 2; ++c) {
                    float2 v = n2[c];
                    s += (cv[2*c]   == mx) ? v.x : 0.f;
                    s += (cv[2*c+1] == mx) ? v.y : 0.f;
                }
            }
            sel[k] = s;
            cnt += (s != 0.f) ? 1 : 0;
        }
        float norm = (cnt > 0) ? 9.f / (float)cnt : 0.f;
        #pragma unroll
        for (int k = 0; k < 9; ++k) sl[k][m] = sel[k] * norm;
    }

    floatx4 O[5][2];
    #pragma unroll
    for (int im = 0; im < 5; ++im)
        #pragma unroll
        for (int jn = 0; jn < 2; ++jn)
            O[im][jn] = (floatx4){0.f, 0.f, 0.f, 0.f};

    __syncthreads();

    // ---- main loop ----
    for (int p = 0; p < 6; ++p) {
        const int buf = p & 1;
        const int i   = p >> 1;
        const int cc  = (p & 1) * 128;

        #pragma unroll
        for (int j = 0; j < 3; ++j) {
            const int k = 3 * i + j;

            // B first (oldest in vmem queue -> MFMA wait doesn't drain staging)
            short8 Breg[8];               // [kk][jn]
            #pragma unroll
            for (int kk = 0; kk < 4; ++kk)
                #pragma unroll
                for (int jn = 0; jn < 2; ++jn)
                    Breg[kk * 2 + jn] = *(const short8*)(wbT
                        + ((size_t)k * 256 + d0 + wv * 32 + jn * 16 + ln) * 256
                        + cc + kk * 32 + quad * 8);

            if (p < 5) sload(p + 1, 2 * j);   // next phase, 2 chunks, in flight

            floatx4 P[5][2];
            #pragma unroll
            for (int im = 0; im < 5; ++im)
                #pragma unroll
                for (int jn = 0; jn < 2; ++jn)
                    P[im][jn] = (floatx4){0.f, 0.f, 0.f, 0.f};

            #pragma unroll
            for (int kk = 0; kk < 4; ++kk) {
                short8 a[5];
                #pragma unroll
                for (int im = 0; im < 5; ++im) {
                    const int rho = im * 16 + ln + j;
                    const int Gc  = 4 * kk + quad;
                    const int ch  = (Gc & 8) | ((Gc ^ rho) & 7);
                    a[im] = *(const short8*)&xs[buf][rho * 128 + ch * 8];
                }
                #pragma unroll
                for (int im = 0; im < 5; ++im)
                    #pragma unroll
                    for (int jn = 0; jn < 2; ++jn)
                        P[im][jn] = __builtin_amdgcn_mfma_f32_16x16x32_bf16(
                            a[im], Breg[kk * 2 + jn], P[im][jn], 0, 0, 0);
            }

            if (p < 5) sstore(buf ^ 1, 2 * j);   // pack+write after MFMA issue

            // O += s_k[m] * P   (row m = im*16 + quad*4 + e; broadcast reads)
            #pragma unroll
            for (int im = 0; im < 5; ++im) {
                const floatx4 sv = *(const floatx4*)&sl[k][im * 16 + quad * 4];
                #pragma unroll
                for (int jn = 0; jn < 2; ++jn) {
                    O[im][jn][0] += sv[0] * P[im][jn][0];
                    O[im][jn][1] += sv[1] * P[im][jn][1];
                    O[im][jn][2] += sv[2] * P[im][jn][2];
                    O[im][jn][3] += sv[3] * P[im][jn][3];
                }
            }
        }
        __syncthreads();                  // buf consumed; buf^1 writes visible
    }

    // epilogue: C/D layout col(d)=lane&15, row(m)=quad*4+reg
    #pragma unroll
    for (int im = 0; im < 5; ++im) {
        #pragma unroll
        for (int jn = 0; jn < 2; ++jn) {
            const int dd = d0 + wv * 32 + jn * 16 + ln;
            #pragma unroll
            for (int r = 0; r < 4; ++r) {
                const int m = im * 16 + quad * 4 + r;
                out[((size_t)(rt * W_ + m)) * DIM_ + dd] = O[im][jn][r];
            }
        }
    }
}

extern "C" void kernel_launch(void* const* d_in, const int* in_sizes, int n_in,
                              void* d_out, int out_size, void* d_ws, size_t ws_size,
                              hipStream_t stream)
{
    const float* x   = (const float*)d_in[0];   // (4,80,80,256) f32
    const float* seg = (const float*)d_in[1];   // (4,80,80,22)  f32
    const float* cw  = (const float*)d_in[2];   // (256,3,3,256) f32
    float* out = (float*)d_out;

    ushort* wbT = (ushort*)d_ws;                           // 1,179,648 B
    ushort* xb  = (ushort*)((char*)d_ws + 1179648);        // 13,107,200 B
    const size_t need = 1179648u + 13107200u;

    if (ws_size >= need) {
        prep<<<dim3(72 + NXB), dim3(256), 0, stream>>>(cw, x, wbT, xb);
        conv5<true><<<dim3(B_ * H_, 2), dim3(256), 0, stream>>>(x, xb, seg, wbT, out);
    } else {
        prep<<<dim3(72), dim3(256), 0, stream>>>(cw, x, wbT, xb);
        conv5<false><<<dim3(B_ * H_, 2), dim3(256), 0, stream>>>(x, nullptr, seg, wbT, out);
    }
}